// Round 4
// baseline (91.451 us; speedup 1.0000x reference)
//
#include <hip/hip_runtime.h>
#include <math.h>

namespace {

// ============================================================================
// DISCRIMINATOR BUILD (round 4): round-3 multipole kernel with the phase-1
// source loop replicated 4x (exact 0.25f rescale of pot/grad/near; self terms
// untouched). Purpose: decide between
//   H-tax : kernel time is a ~20-25us work-independent dispatch-context tax
//           (clock ramp / L2 writeback after the 256MiB fill)  -> wall ~75-82
//   H-work: kernel time scales with the pair loop               -> wall ~140+,
//           es_main surfaces in top-5 with its counter row.
// Math unchanged: all replicated contributions are scaled by 0.25f exactly.
// asm clobber per pass prevents cross-pass CSE (rule #17).
// ============================================================================

constexpr int   MTOT = 4096;
constexpr float H    = 0.1f;

constexpr float W0 = 0.45276925690687087f;
constexpr float W1 = 0.66708320320631664f;
constexpr float W2 = 0.91923881554251174f;
constexpr float W3 = 1.18532695911296985f;

constexpr float KCOUL   = 14.399645478425669f;
constexpr float HALF_L1 = 2.8867513459481287f;
constexpr float SQRTPI  = 1.7724538509055159f;

// A&S 7.1.25: erf(k d) = 1 - t(a1+a2 t+a3 t^2) * 2^(c2 d^2), t=1/(1+pk d)
constexpr float PK[4] = {0.5195472f, 0.3526314f, 0.2559019f, 0.1984558f};
constexpr float C2[4] = {-1.7593842f, -0.8105028f, -0.4268329f, -0.2567073f};
constexpr float EA1 = 0.3480242f, EA2 = -0.0958798f, EA3 = 0.7478556f;
constexpr float RCP_H = 9.9999000f, RCP_HS2 = 7.0710178f, RCP_2H = 4.9999750f;

// KA_r = 2 k_r / sqrt(pi)   (dE/dd = KA * 2^(C2 d^2));  K2X_r = 2 k_r^2
constexpr float KA[4]  = {1.2460860f, 0.84575637f, 0.61375334f, 0.47597746f};
constexpr float K2X[4] = {2.4390243f, 1.1235959f, 0.59171598f, 0.35587189f};

constexpr float NEAR2   = 6.25f;   // exact path when center-d < 2.5
constexpr int   NEARCAP = 256;

constexpr int   NPASS   = 4;
constexpr float INV_NPASS = 0.25f;

__device__ __forceinline__ float fast_rcp(float x)  { return __builtin_amdgcn_rcpf(x); }
__device__ __forceinline__ float fast_rsq(float x)  { return __builtin_amdgcn_rsqf(x); }
__device__ __forceinline__ float fast_exp2(float x) { return __builtin_amdgcn_exp2f(x); }

__device__ __forceinline__ float erf_q(float d, float d2, float pk, float c2) {
  float t = fast_rcp(__builtin_fmaf(d, pk, 1.0f));
  float poly = t * __builtin_fmaf(t, __builtin_fmaf(t, EA3, EA2), EA1);
  return poly * fast_exp2(d2 * c2);
}

__device__ __forceinline__ float project_one(const float* S, int k) {
  if (k < 4) return S[k];
  int q = k - 4;
  int r = q / 3;
  int comp = q - 3 * r;
  int j1, j2;
  if (comp == 0)      { j1 = 2; j2 = 5; }
  else if (comp == 1) { j1 = 3; j2 = 6; }
  else                { j1 = 1; j2 = 4; }
  return HALF_L1 * (S[j1 * 4 + r] - S[j2 * 4 + r]);
}

__device__ __forceinline__ float offx(int a) { return (a == 1) ? H : (a == 4) ? -H : 0.0f; }
__device__ __forceinline__ float offy(int a) { return (a == 2) ? H : (a == 5) ? -H : 0.0f; }
__device__ __forceinline__ float offz(int a) { return (a == 3) ? H : (a == 6) ? -H : 0.0f; }

__global__ __launch_bounds__(256, 4) void es_main(
    const float* __restrict__ sf,   // (4096, 4)
    const float* __restrict__ pos,  // (4096, 3)
    float* __restrict__ out)        // [0:65536) features, [65536:131072) self_terms
{
  __shared__ float4 s_pos4[128];
  __shared__ float4 s_chg4[128];      // {s0, 5*s3, 5*s1, 5*s2}
  __shared__ float  s_red[4][16];     // per-node: pot[4], gx[4], gy[4], gz[4]
  __shared__ float  s_nearS[4][7][4]; // near-pair exact site contributions
  __shared__ int    s_nearI[NEARCAP];
  __shared__ int    s_ncnt;
  __shared__ float  s_feat[4 * 28];
  __shared__ float  s_self[4 * 28];

  const int b   = blockIdx.x;
  const int g   = b >> 5;    // graph
  const int grp = b & 31;    // node group (4 nodes)
  const int tid = threadIdx.x;
  const int t   = tid >> 6;  // target node 0..3 (= wave id)
  const int c   = tid & 63;  // source lane

  if (tid < 128) {
    const float* p = pos + (size_t)(g * 128 + tid) * 3;
    const float4 s = ((const float4*)sf)[g * 128 + tid];
    s_pos4[tid] = make_float4(p[0], p[1], p[2], 0.0f);
    s_chg4[tid] = make_float4(s.x, 5.0f * s.w, 5.0f * s.y, 5.0f * s.z);
  }
  if (tid < 112) ((float*)s_nearS)[tid] = 0.0f;
  if (tid == 0) s_ncnt = 0;
  __syncthreads();

  const int own = grp * 4 + t;
  const float4 cp = s_pos4[own];

  float acc[16];
#pragma unroll
  for (int k = 0; k < 16; ++k) acc[k] = 0.0f;

  // ---- phase 1 (replicated NPASS x): branchless multipole pot+grad ----
  for (int pass = 0; pass < NPASS; ++pass) {
    float qx = cp.x, qy = cp.y, qz = cp.z;
    asm volatile("" : "+v"(qx), "+v"(qy), "+v"(qz));   // opaque per pass
#pragma unroll
    for (int si = 0; si < 2; ++si) {
      const int j = c + 64 * si;
      if (j != own) {
        const float4 p4 = s_pos4[j];
        const float4 c4 = s_chg4[j];
        const float vx = qx - p4.x;
        const float vy = qy - p4.y;
        const float vz = qz - p4.z;
        const float d2 = __builtin_fmaf(vx, vx, __builtin_fmaf(vy, vy, vz * vz));
        if (d2 < NEAR2) {
          int slot = atomicAdd(&s_ncnt, 1);
          if (slot < NEARCAP) s_nearI[slot] = (t << 8) | j;   // 4x duplicates, rescaled later
        } else {
          const float rd  = fast_rsq(d2);
          const float d   = d2 * rd;
          const float rd2 = rd * rd;
          const float rd3 = rd2 * rd;
          const float rd4 = rd2 * rd2;
          const float S3  = 3.0f * rd3;
          const float S4  = 3.0f * rd4;
          const float dot = __builtin_fmaf(c4.y, vx, __builtin_fmaf(c4.z, vy, c4.w * vz));
          const float dp  = 0.2f * dot;
          const float c0  = c4.x;
#pragma unroll
          for (int r = 0; r < 4; ++r) {
            const float tt = fast_rcp(__builtin_fmaf(d, PK[r], 1.0f));
            const float X  = fast_exp2(d2 * C2[r]);
            const float q  = tt * __builtin_fmaf(tt, __builtin_fmaf(tt, EA3, EA2), EA1) * X;
            const float E  = 1.0f - q;
            const float A  = KA[r] * X;
            const float gv = E * rd;
            const float gp = (A - gv) * rd;
            const float Bv = -gp * rd;
            const float h1 = __builtin_fmaf(K2X[r], rd, S3);
            const float Bp = __builtin_fmaf(A, h1, -(E * S4));
            acc[r] = __builtin_fmaf(dp, Bv, __builtin_fmaf(c0, gv, acc[r]));
            const float sv  = __builtin_fmaf(dp, Bp, c0 * gp) * rd;
            const float B02 = 0.2f * Bv;
            acc[4 + r]  = __builtin_fmaf(sv, vx, __builtin_fmaf(B02, c4.y, acc[4 + r]));
            acc[8 + r]  = __builtin_fmaf(sv, vy, __builtin_fmaf(B02, c4.z, acc[8 + r]));
            acc[12 + r] = __builtin_fmaf(sv, vz, __builtin_fmaf(B02, c4.w, acc[12 + r]));
          }
        }
      }
    }
  }

  // ---- full-wave reduction over the 64 source lanes ----
#pragma unroll
  for (int k = 0; k < 16; ++k) {
    float v = acc[k];
    v += __shfl_xor(v, 1);
    v += __shfl_xor(v, 2);
    v += __shfl_xor(v, 4);
    v += __shfl_xor(v, 8);
    v += __shfl_xor(v, 16);
    v += __shfl_xor(v, 32);
    acc[k] = v;
  }
  if (c == 0) {
#pragma unroll
    for (int k = 0; k < 16; ++k) s_red[t][k] = acc[k];
  }
  __syncthreads();

  // ---- phase 2: near list (4x duplicated), exact 7x7, wave-dense ----
  const int N = (s_ncnt < NEARCAP) ? s_ncnt : NEARCAP;
  for (int e = t; e < N; e += 4) {
    const int ent = s_nearI[e];
    const int tt  = ent >> 8;
    const int j   = ent & 127;
    const int a   = c >> 3;
    const int i   = c & 7;
    const bool act = (a < 7) && (i < 7);
    const float4 tp = s_pos4[grp * 4 + tt];
    const float4 p4 = s_pos4[j];
    const float4 c4 = s_chg4[j];
    const float ci = !act ? 0.0f :
                     (i == 0) ?  c4.x : (i == 1) ?  c4.y : (i == 2) ?  c4.z :
                     (i == 3) ?  c4.w : (i == 4) ? -c4.y : (i == 5) ? -c4.z : -c4.w;
    const float sx = tp.x - p4.x + offx(a) - offx(i);
    const float sy = tp.y - p4.y + offy(a) - offy(i);
    const float sz = tp.z - p4.z + offz(a) - offz(i);
    const float d2 = fmaxf(__builtin_fmaf(sx, sx, __builtin_fmaf(sy, sy, sz * sz)), 1e-12f);
    const float rd = fast_rsq(d2);
    const float d  = d2 * rd;
    const float cv = ci * rd;
    float vr[4];
#pragma unroll
    for (int r = 0; r < 4; ++r) {
      const float tt2 = fast_rcp(__builtin_fmaf(d, PK[r], 1.0f));
      const float q   = tt2 * __builtin_fmaf(tt2, __builtin_fmaf(tt2, EA3, EA2), EA1)
                            * fast_exp2(d2 * C2[r]);
      vr[r] = cv * (1.0f - q);
    }
#pragma unroll
    for (int r = 0; r < 4; ++r) {
      float v = vr[r];
      v += __shfl_xor(v, 1);
      v += __shfl_xor(v, 2);
      v += __shfl_xor(v, 4);
      vr[r] = v;
    }
    if (i == 0 && a < 7) {
#pragma unroll
      for (int r = 0; r < 4; ++r) atomicAdd(&s_nearS[tt][a][r], vr[r]);
    }
  }
  __syncthreads();

  // ---- epilogue: site values (0.25 * replicated sums) + self terms ----
  if (tid < 112) {
    const int node = tid / 28;
    const int rem  = tid - node * 28;
    const int a    = rem >> 2;
    const int r    = rem & 3;

    const float pot = s_red[node][r];
    const float gx  = s_red[node][4 + r];
    const float gy  = s_red[node][8 + r];
    const float gz  = s_red[node][12 + r];
    const float od  = (a == 1) ?  H * gx : (a == 2) ?  H * gy : (a == 3) ?  H * gz :
                      (a == 4) ? -H * gx : (a == 5) ? -H * gy : (a == 6) ? -H * gz : 0.0f;
    const float mid = INV_NPASS * (pot + od + s_nearS[node][a][r]);

    const float w  = (r == 0) ? W0 : (r == 1) ? W1 : (r == 2) ? W2 : W3;
    const float pk = PK[r];
    const float c2 = C2[r];
    const float diag = fast_rcp(w * SQRTPI);
    const float ph1 = (1.f - erf_q(0.1f,        0.01f, pk, c2)) * RCP_H;
    const float ph2 = (1.f - erf_q(0.14142136f, 0.02f, pk, c2)) * RCP_HS2;
    const float ph3 = (1.f - erf_q(0.2f,        0.04f, pk, c2)) * RCP_2H;

    const float4 c4 = s_chg4[grp * 4 + node];
    float selfSum = 0.f;
#pragma unroll
    for (int i = 0; i < 7; ++i) {
      const float ci = (i == 0) ?  c4.x : (i == 1) ?  c4.y : (i == 2) ?  c4.z :
                       (i == 3) ?  c4.w : (i == 4) ? -c4.y : (i == 5) ? -c4.z : -c4.w;
      float ph;
      if (i == a)                            ph = diag;
      else if (i == 0 || a == 0)             ph = ph1;
      else if ((i - a == 3) || (a - i == 3)) ph = ph3;
      else                                   ph = ph2;
      selfSum = __builtin_fmaf(ci, ph, selfSum);
    }
    const float sv = KCOUL * selfSum;
    s_self[tid] = sv;
    s_feat[tid] = __builtin_fmaf(KCOUL, mid, sv);
  }
  __syncthreads();

  if (tid < 64) {
    const int node = tid >> 4;
    const int k    = tid & 15;
    const int m    = g * 128 + grp * 4 + node;
    out[m * 16 + k]             = project_one(&s_feat[node * 28], k);
    out[MTOT * 16 + m * 16 + k] = project_one(&s_self[node * 28], k);
  }
}

} // namespace

extern "C" void kernel_launch(void* const* d_in, const int* in_sizes, int n_in,
                              void* d_out, int out_size, void* d_ws, size_t ws_size,
                              hipStream_t stream) {
  const float* sf  = (const float*)d_in[0];   // source_feats (4096,1,4)
  const float* pos = (const float*)d_in[1];   // node_positions (4096,3)
  float* out = (float*)d_out;
  es_main<<<1024, 256, 0, stream>>>(sf, pos, out);
}

// Round 6
// 68.906 us; speedup vs baseline: 1.3272x; 1.3272x over previous
//
#include <hip/hip_runtime.h>
#include <math.h>

namespace {

// ============================================================================
// One wave per target node. 4096 blocks x 64 threads; zero LDS, zero
// __syncthreads, zero atomics. Each lane holds 2 source nodes in registers;
// far-field = source-collapsed (monopole+dipole) potential + analytic
// gradient per radial (target-side collapse: l1 via 2h*grad). Near sources
// (center-d < 2.5, ~3 per target) are found with __ballot and processed
// inline by the whole wave with the exact 7x7 site-site path. Reduction =
// 64-lane shfl butterfly; epilogue + projection via intra-wave shfl.
// Numerics identical to the round-3 passing kernel.
// (Resubmission of round-4 source: round-5 bench was a container/infra
// failure, not a kernel result — code unchanged to keep the A/B clean.)
// ============================================================================

constexpr int   MTOT = 4096;
constexpr float H    = 0.1f;

constexpr float W0 = 0.45276925690687087f;
constexpr float W1 = 0.66708320320631664f;
constexpr float W2 = 0.91923881554251174f;
constexpr float W3 = 1.18532695911296985f;

constexpr float KCOUL   = 14.399645478425669f;
constexpr float HALF_L1 = 2.8867513459481287f;
constexpr float SQRTPI  = 1.7724538509055159f;

// A&S 7.1.25: erf(k d) = 1 - t(a1+a2 t+a3 t^2) * 2^(c2 d^2), t=1/(1+pk d)
constexpr float PK[4] = {0.5195472f, 0.3526314f, 0.2559019f, 0.1984558f};
constexpr float C2[4] = {-1.7593842f, -0.8105028f, -0.4268329f, -0.2567073f};
constexpr float EA1 = 0.3480242f, EA2 = -0.0958798f, EA3 = 0.7478556f;
constexpr float RCP_H = 9.9999000f, RCP_HS2 = 7.0710178f, RCP_2H = 4.9999750f;

// KA_r = 2 k_r / sqrt(pi);  K2X_r = 2 k_r^2
constexpr float KA[4]  = {1.2460860f, 0.84575637f, 0.61375334f, 0.47597746f};
constexpr float K2X[4] = {2.4390243f, 1.1235959f, 0.59171598f, 0.35587189f};

constexpr float NEAR2 = 6.25f;   // exact 7x7 path when center-d < 2.5

__device__ __forceinline__ float fast_rcp(float x)  { return __builtin_amdgcn_rcpf(x); }
__device__ __forceinline__ float fast_rsq(float x)  { return __builtin_amdgcn_rsqf(x); }
__device__ __forceinline__ float fast_exp2(float x) { return __builtin_amdgcn_exp2f(x); }

__device__ __forceinline__ float erf_q(float d, float d2, float pk, float c2) {
  float t = fast_rcp(__builtin_fmaf(d, pk, 1.0f));
  float poly = t * __builtin_fmaf(t, __builtin_fmaf(t, EA3, EA2), EA1);
  return poly * fast_exp2(d2 * c2);
}

__device__ __forceinline__ float offx(int a) { return (a == 1) ? H : (a == 4) ? -H : 0.0f; }
__device__ __forceinline__ float offy(int a) { return (a == 2) ? H : (a == 5) ? -H : 0.0f; }
__device__ __forceinline__ float offz(int a) { return (a == 3) ? H : (a == 6) ? -H : 0.0f; }

__global__ __launch_bounds__(64, 4) void es_main(
    const float* __restrict__ sf,   // (4096, 4)
    const float* __restrict__ pos,  // (4096, 3)
    float* __restrict__ out)        // [0:65536) features, [65536:131072) self_terms
{
  const int b    = blockIdx.x;       // global target node (graph = b>>7)
  const int base = b & ~127;         // first node of this graph
  const int c    = threadIdx.x;      // lane 0..63

  // target center + own charges (wave-uniform loads, cache-broadcast)
  const float tx = pos[(size_t)b * 3 + 0];
  const float ty = pos[(size_t)b * 3 + 1];
  const float tz = pos[(size_t)b * 3 + 2];
  const float4 os = ((const float4*)sf)[b];
  const float4 oc = make_float4(os.x, 5.0f * os.w, 5.0f * os.y, 5.0f * os.z);

  float acc[16];
#pragma unroll
  for (int k = 0; k < 16; ++k) acc[k] = 0.0f;
  float nacc0 = 0.f, nacc1 = 0.f, nacc2 = 0.f, nacc3 = 0.f;  // near site sums (lanes a*8)

  const int a_sub = c >> 3;   // near-path target sub-site 0..7 (7 inactive)
  const int i_sub = c & 7;    // near-path source sub-site 0..7 (7 inactive)

#pragma unroll
  for (int si = 0; si < 2; ++si) {
    const int j = base + c + 64 * si;
    // per-lane source loads (coalesced)
    const float px = pos[(size_t)j * 3 + 0];
    const float py = pos[(size_t)j * 3 + 1];
    const float pz = pos[(size_t)j * 3 + 2];
    const float4 s4 = ((const float4*)sf)[j];
    const float cx = s4.x, cy = 5.0f * s4.w, cz = 5.0f * s4.y, cw = 5.0f * s4.z;

    const float vx = tx - px;
    const float vy = ty - py;
    const float vz = tz - pz;
    const float d2 = __builtin_fmaf(vx, vx, __builtin_fmaf(vy, vy, vz * vz));
    const bool self  = (j == b);
    const bool nearp = (d2 < NEAR2) && !self;

    if (!self && !nearp) {
      // ---- far field: collapsed source, potential + gradient ----
      const float rd  = fast_rsq(d2);
      const float d   = d2 * rd;
      const float rd2 = rd * rd;
      const float rd3 = rd2 * rd;
      const float rd4 = rd2 * rd2;
      const float S3  = 3.0f * rd3;
      const float S4  = 3.0f * rd4;
      const float dot = __builtin_fmaf(cy, vx, __builtin_fmaf(cz, vy, cw * vz));
      const float dp  = 0.2f * dot;
#pragma unroll
      for (int r = 0; r < 4; ++r) {
        const float tt = fast_rcp(__builtin_fmaf(d, PK[r], 1.0f));
        const float X  = fast_exp2(d2 * C2[r]);
        const float q  = tt * __builtin_fmaf(tt, __builtin_fmaf(tt, EA3, EA2), EA1) * X;
        const float E  = 1.0f - q;
        const float A  = KA[r] * X;
        const float gv = E * rd;
        const float gp = (A - gv) * rd;
        const float Bv = -gp * rd;
        const float h1 = __builtin_fmaf(K2X[r], rd, S3);
        const float Bp = __builtin_fmaf(A, h1, -(E * S4));
        acc[r] = __builtin_fmaf(dp, Bv, __builtin_fmaf(cx, gv, acc[r]));
        const float sv  = __builtin_fmaf(dp, Bp, cx * gp) * rd;
        const float B02 = 0.2f * Bv;
        acc[4 + r]  = __builtin_fmaf(sv, vx, __builtin_fmaf(B02, cy, acc[4 + r]));
        acc[8 + r]  = __builtin_fmaf(sv, vy, __builtin_fmaf(B02, cz, acc[8 + r]));
        acc[12 + r] = __builtin_fmaf(sv, vz, __builtin_fmaf(B02, cw, acc[12 + r]));
      }
    }

    // ---- near sources: whole wave processes each, exact 7x7 ----
    unsigned long long m = __ballot(nearp);
    while (m) {
      const int src = __ffsll(m) - 1;
      m &= m - 1;
      const float qx = __shfl(px, src), qy = __shfl(py, src), qz = __shfl(pz, src);
      const float bx = __shfl(cx, src), by = __shfl(cy, src);
      const float bz = __shfl(cz, src), bw = __shfl(cw, src);
      const bool act = (a_sub < 7) && (i_sub < 7);
      const float ci = !act ? 0.0f :
                       (i_sub == 0) ?  bx : (i_sub == 1) ?  by : (i_sub == 2) ?  bz :
                       (i_sub == 3) ?  bw : (i_sub == 4) ? -by : (i_sub == 5) ? -bz : -bw;
      const float sx = tx - qx + offx(a_sub) - offx(i_sub);
      const float sy = ty - qy + offy(a_sub) - offy(i_sub);
      const float sz = tz - qz + offz(a_sub) - offz(i_sub);
      const float dn2 = fmaxf(__builtin_fmaf(sx, sx, __builtin_fmaf(sy, sy, sz * sz)), 1e-12f);
      const float rdn = fast_rsq(dn2);
      const float dn  = dn2 * rdn;
      const float cv  = ci * rdn;
      float vr[4];
#pragma unroll
      for (int r = 0; r < 4; ++r) {
        const float tt = fast_rcp(__builtin_fmaf(dn, PK[r], 1.0f));
        const float q  = tt * __builtin_fmaf(tt, __builtin_fmaf(tt, EA3, EA2), EA1)
                            * fast_exp2(dn2 * C2[r]);
        vr[r] = cv * (1.0f - q);
      }
      // reduce over source sub-site within each 8-lane group
#pragma unroll
      for (int r = 0; r < 4; ++r) {
        float v = vr[r];
        v += __shfl_xor(v, 1);
        v += __shfl_xor(v, 2);
        v += __shfl_xor(v, 4);
        vr[r] = v;
      }
      if (i_sub == 0) {  // lanes 0,8,..,56 hold site a_sub sums
        nacc0 += vr[0]; nacc1 += vr[1]; nacc2 += vr[2]; nacc3 += vr[3];
      }
    }
  }

  // ---- 64-lane butterfly: every lane ends with the full sums ----
#pragma unroll
  for (int k = 0; k < 16; ++k) {
    float v = acc[k];
    v += __shfl_xor(v, 1);
    v += __shfl_xor(v, 2);
    v += __shfl_xor(v, 4);
    v += __shfl_xor(v, 8);
    v += __shfl_xor(v, 16);
    v += __shfl_xor(v, 32);
    acc[k] = v;
  }

  // ---- epilogue: lane l<28 owns (sub-site a, radial r) ----
  const int l = (c < 28) ? c : 0;
  const int a = l >> 2;
  const int r = l & 3;

  const float pot = (r == 0) ? acc[0]  : (r == 1) ? acc[1]  : (r == 2) ? acc[2]  : acc[3];
  const float gx  = (r == 0) ? acc[4]  : (r == 1) ? acc[5]  : (r == 2) ? acc[6]  : acc[7];
  const float gy  = (r == 0) ? acc[8]  : (r == 1) ? acc[9]  : (r == 2) ? acc[10] : acc[11];
  const float gz  = (r == 0) ? acc[12] : (r == 1) ? acc[13] : (r == 2) ? acc[14] : acc[15];

  const float n0 = __shfl(nacc0, a * 8);
  const float n1 = __shfl(nacc1, a * 8);
  const float n2 = __shfl(nacc2, a * 8);
  const float n3 = __shfl(nacc3, a * 8);
  const float nearS = (r == 0) ? n0 : (r == 1) ? n1 : (r == 2) ? n2 : n3;

  const float od = (a == 1) ?  H * gx : (a == 2) ?  H * gy : (a == 3) ?  H * gz :
                   (a == 4) ? -H * gx : (a == 5) ? -H * gy : (a == 6) ? -H * gz : 0.0f;
  const float mid = pot + od + nearS;

  const float w   = (r == 0) ? W0    : (r == 1) ? W1    : (r == 2) ? W2    : W3;
  const float pk  = (r == 0) ? PK[0] : (r == 1) ? PK[1] : (r == 2) ? PK[2] : PK[3];
  const float c2v = (r == 0) ? C2[0] : (r == 1) ? C2[1] : (r == 2) ? C2[2] : C2[3];
  const float diag = fast_rcp(w * SQRTPI);
  const float ph1 = (1.f - erf_q(0.1f,        0.01f, pk, c2v)) * RCP_H;
  const float ph2 = (1.f - erf_q(0.14142136f, 0.02f, pk, c2v)) * RCP_HS2;
  const float ph3 = (1.f - erf_q(0.2f,        0.04f, pk, c2v)) * RCP_2H;

  float selfSum = 0.f;
#pragma unroll
  for (int i = 0; i < 7; ++i) {
    const float ci = (i == 0) ?  oc.x : (i == 1) ?  oc.y : (i == 2) ?  oc.z :
                     (i == 3) ?  oc.w : (i == 4) ? -oc.y : (i == 5) ? -oc.z : -oc.w;
    float ph;
    if (i == a)                            ph = diag;
    else if (i == 0 || a == 0)             ph = ph1;
    else if ((i - a == 3) || (a - i == 3)) ph = ph3;
    else                                   ph = ph2;
    selfSum = __builtin_fmaf(ci, ph, selfSum);
  }
  const float selfv = KCOUL * selfSum;
  const float featv = __builtin_fmaf(KCOUL, mid, selfv);

  // ---- projection via shfl; lanes 0..15 write features, 16..31 self ----
  const int k = (c < 16) ? c : (c < 32 ? c - 16 : 0);
  int idx1, idx2;
  if (k < 4) {
    idx1 = k; idx2 = 0;
  } else {
    const int q  = k - 4;
    const int rr = q / 3;
    const int comp = q - 3 * rr;
    const int j1 = (comp == 0) ? 2 : (comp == 1) ? 3 : 1;
    const int j2 = (comp == 0) ? 5 : (comp == 1) ? 6 : 4;
    idx1 = j1 * 4 + rr; idx2 = j2 * 4 + rr;
  }
  const float f1 = __shfl(featv, idx1), f2 = __shfl(featv, idx2);
  const float s1 = __shfl(selfv, idx1), s2 = __shfl(selfv, idx2);
  const float F  = (k < 4) ? f1 : HALF_L1 * (f1 - f2);
  const float S  = (k < 4) ? s1 : HALF_L1 * (s1 - s2);

  if (c < 16)      out[(size_t)b * 16 + c] = F;
  else if (c < 32) out[(size_t)MTOT * 16 + (size_t)b * 16 + (c - 16)] = S;
}

} // namespace

extern "C" void kernel_launch(void* const* d_in, const int* in_sizes, int n_in,
                              void* d_out, int out_size, void* d_ws, size_t ws_size,
                              hipStream_t stream) {
  const float* sf  = (const float*)d_in[0];   // source_feats (4096,1,4)
  const float* pos = (const float*)d_in[1];   // node_positions (4096,3)
  float* out = (float*)d_out;
  es_main<<<4096, 64, 0, stream>>>(sf, pos, out);
}

// Round 7
// 67.572 us; speedup vs baseline: 1.3534x; 1.0197x over previous
//
#include <hip/hip_runtime.h>
#include <math.h>

namespace {

// ============================================================================
// One wave per target node (r6 structure) + pipe rebalance:
//  - butterfly reductions via DPP row_ror (VALU) + xor16/32 only on LDS pipe
//  - near-source broadcasts via v_readlane (scalar) instead of ds_bpermute
//  - self-term phi matrix folded to 12 host-precomputed exact-erf constants
//    (self(0,r)=oc.x*diag_r ; self(a,r)=oc.x*ph1_r +/- q_a*(diag_r-ph3_r))
// Far/near numerics identical to the passing round-6 kernel.
// ============================================================================

constexpr int   MTOT = 4096;
constexpr float H    = 0.1f;

constexpr float KCOUL   = 14.399645478425669f;
constexpr float HALF_L1 = 2.8867513459481287f;

// A&S 7.1.25: erf(k d) = 1 - t(a1+a2 t+a3 t^2) * 2^(c2 d^2), t=1/(1+pk d)
constexpr float PK[4] = {0.5195472f, 0.3526314f, 0.2559019f, 0.1984558f};
constexpr float C2[4] = {-1.7593842f, -0.8105028f, -0.4268329f, -0.2567073f};
constexpr float EA1 = 0.3480242f, EA2 = -0.0958798f, EA3 = 0.7478556f;

// KA_r = 2 k_r / sqrt(pi) ( == diag_r = 1/(W_r sqrt(pi)) );  K2X_r = 2 k_r^2
constexpr float KA[4]  = {1.2460860f, 0.84575637f, 0.61375334f, 0.47597746f};
constexpr float K2X[4] = {2.4390243f, 1.1235959f, 0.59171598f, 0.35587189f};

// self-term constants (exact erf, host-precomputed):
// PH1_r = erf(0.1 k_r)/(0.1+1e-6);  DD_r = diag_r - erf(0.2 k_r)/(0.2+1e-6)
constexpr float PH1C[4] = {1.2410270f, 0.84416626f, 0.61314637f, 0.47569094f};
constexpr float DDC[4]  = {0.01997438f, 0.00629767f, 0.00241240f, 0.00112878f};

constexpr float NEAR2 = 6.25f;   // exact 7x7 path when center-d < 2.5

__device__ __forceinline__ float fast_rcp(float x)  { return __builtin_amdgcn_rcpf(x); }
__device__ __forceinline__ float fast_rsq(float x)  { return __builtin_amdgcn_rsqf(x); }
__device__ __forceinline__ float fast_exp2(float x) { return __builtin_amdgcn_exp2f(x); }

// DPP add: v += lane-permuted v (VALU pipe, no LDS traffic)
template <int CTRL>
__device__ __forceinline__ float dpp_add(float v) {
  const int p = __builtin_amdgcn_update_dpp(0, __float_as_int(v), CTRL, 0xf, 0xf, true);
  return v + __int_as_float(p);
}
// sum within each 16-lane row: row_ror 8,4,2,1 (rotation group covers the row)
__device__ __forceinline__ float row16_sum(float v) {
  v = dpp_add<0x128>(v);
  v = dpp_add<0x124>(v);
  v = dpp_add<0x122>(v);
  v = dpp_add<0x121>(v);
  return v;
}
__device__ __forceinline__ float wave_sum(float v) {
  v = row16_sum(v);
  v += __shfl_xor(v, 16);
  v += __shfl_xor(v, 32);
  return v;
}
// sum over stride-8 lane classes (xor8 via ror8 within 16, then xor16/32)
__device__ __forceinline__ float stride8_sum(float v) {
  v = dpp_add<0x128>(v);
  v += __shfl_xor(v, 16);
  v += __shfl_xor(v, 32);
  return v;
}

__device__ __forceinline__ float bcast_lane(float v, int src) {
  return __int_as_float(__builtin_amdgcn_readlane(__float_as_int(v), src));
}

__device__ __forceinline__ float offx(int a) { return (a == 1) ? H : (a == 4) ? -H : 0.0f; }
__device__ __forceinline__ float offy(int a) { return (a == 2) ? H : (a == 5) ? -H : 0.0f; }
__device__ __forceinline__ float offz(int a) { return (a == 3) ? H : (a == 6) ? -H : 0.0f; }

__global__ __launch_bounds__(64, 4) void es_main(
    const float* __restrict__ sf,   // (4096, 4)
    const float* __restrict__ pos,  // (4096, 3)
    float* __restrict__ out)        // [0:65536) features, [65536:131072) self_terms
{
  const int b    = blockIdx.x;       // global target node (graph = b>>7)
  const int base = b & ~127;         // first node of this graph
  const int c    = threadIdx.x;      // lane 0..63

  const float tx = pos[(size_t)b * 3 + 0];
  const float ty = pos[(size_t)b * 3 + 1];
  const float tz = pos[(size_t)b * 3 + 2];
  const float4 os = ((const float4*)sf)[b];
  const float4 oc = make_float4(os.x, 5.0f * os.w, 5.0f * os.y, 5.0f * os.z);

  float acc[16];
#pragma unroll
  for (int k = 0; k < 16; ++k) acc[k] = 0.0f;
  float nacc0 = 0.f, nacc1 = 0.f, nacc2 = 0.f, nacc3 = 0.f;  // near sums (lanes 0..6 = a)

  const int a_sub = c & 7;    // near-path target sub-site 0..7 (7 inactive)
  const int i_sub = c >> 3;   // near-path source sub-site 0..7 (7 inactive)

#pragma unroll
  for (int si = 0; si < 2; ++si) {
    const int j = base + c + 64 * si;
    const float px = pos[(size_t)j * 3 + 0];
    const float py = pos[(size_t)j * 3 + 1];
    const float pz = pos[(size_t)j * 3 + 2];
    const float4 s4 = ((const float4*)sf)[j];
    const float cx = s4.x, cy = 5.0f * s4.w, cz = 5.0f * s4.y, cw = 5.0f * s4.z;

    const float vx = tx - px;
    const float vy = ty - py;
    const float vz = tz - pz;
    const float d2 = __builtin_fmaf(vx, vx, __builtin_fmaf(vy, vy, vz * vz));
    const bool self  = (j == b);
    const bool nearp = (d2 < NEAR2) && !self;

    if (!self && !nearp) {
      // ---- far field: collapsed source, potential + gradient ----
      const float rd  = fast_rsq(d2);
      const float d   = d2 * rd;
      const float rd2 = rd * rd;
      const float rd3 = rd2 * rd;
      const float rd4 = rd2 * rd2;
      const float S3  = 3.0f * rd3;
      const float S4  = 3.0f * rd4;
      const float dot = __builtin_fmaf(cy, vx, __builtin_fmaf(cz, vy, cw * vz));
      const float dp  = 0.2f * dot;
#pragma unroll
      for (int r = 0; r < 4; ++r) {
        const float tt = fast_rcp(__builtin_fmaf(d, PK[r], 1.0f));
        const float X  = fast_exp2(d2 * C2[r]);
        const float q  = tt * __builtin_fmaf(tt, __builtin_fmaf(tt, EA3, EA2), EA1) * X;
        const float E  = 1.0f - q;
        const float A  = KA[r] * X;
        const float gv = E * rd;
        const float gp = (A - gv) * rd;
        const float Bv = -gp * rd;
        const float h1 = __builtin_fmaf(K2X[r], rd, S3);
        const float Bp = __builtin_fmaf(A, h1, -(E * S4));
        acc[r] = __builtin_fmaf(dp, Bv, __builtin_fmaf(cx, gv, acc[r]));
        const float sv  = __builtin_fmaf(dp, Bp, cx * gp) * rd;
        const float B02 = 0.2f * Bv;
        acc[4 + r]  = __builtin_fmaf(sv, vx, __builtin_fmaf(B02, cy, acc[4 + r]));
        acc[8 + r]  = __builtin_fmaf(sv, vy, __builtin_fmaf(B02, cz, acc[8 + r]));
        acc[12 + r] = __builtin_fmaf(sv, vz, __builtin_fmaf(B02, cw, acc[12 + r]));
      }
    }

    // ---- near sources: wave-uniform loop; scalar broadcast via readlane ----
    unsigned long long m = __ballot(nearp);
    while (m) {
      const int src = __ffsll(m) - 1;
      m &= m - 1;
      const float qx = bcast_lane(px, src), qy = bcast_lane(py, src), qz = bcast_lane(pz, src);
      const float bx = bcast_lane(cx, src), by = bcast_lane(cy, src);
      const float bz = bcast_lane(cz, src), bw = bcast_lane(cw, src);
      const bool act = (a_sub < 7) && (i_sub < 7);
      const float ci = !act ? 0.0f :
                       (i_sub == 0) ?  bx : (i_sub == 1) ?  by : (i_sub == 2) ?  bz :
                       (i_sub == 3) ?  bw : (i_sub == 4) ? -by : (i_sub == 5) ? -bz : -bw;
      const float sx = tx - qx + offx(a_sub) - offx(i_sub);
      const float sy = ty - qy + offy(a_sub) - offy(i_sub);
      const float sz = tz - qz + offz(a_sub) - offz(i_sub);
      const float dn2 = fmaxf(__builtin_fmaf(sx, sx, __builtin_fmaf(sy, sy, sz * sz)), 1e-12f);
      const float rdn = fast_rsq(dn2);
      const float dn  = dn2 * rdn;
      const float cv  = ci * rdn;
      float vr[4];
#pragma unroll
      for (int r = 0; r < 4; ++r) {
        const float tt = fast_rcp(__builtin_fmaf(dn, PK[r], 1.0f));
        const float q  = tt * __builtin_fmaf(tt, __builtin_fmaf(tt, EA3, EA2), EA1)
                            * fast_exp2(dn2 * C2[r]);
        vr[r] = cv * (1.0f - q);
      }
      // reduce over source sub-site i_sub (stride-8 lane classes)
#pragma unroll
      for (int r = 0; r < 4; ++r) vr[r] = stride8_sum(vr[r]);
      if (i_sub == 0) {  // lanes 0..7 hold the a_sub = c sums
        nacc0 += vr[0]; nacc1 += vr[1]; nacc2 += vr[2]; nacc3 += vr[3];
      }
    }
  }

  // ---- 64-lane reduction (DPP rows + 2 LDS-pipe steps per value) ----
#pragma unroll
  for (int k = 0; k < 16; ++k) acc[k] = wave_sum(acc[k]);

  // ---- epilogue: lane l<28 owns (sub-site a, radial r) ----
  const int l = (c < 28) ? c : 0;
  const int a = l >> 2;
  const int r = l & 3;

  const float pot = (r == 0) ? acc[0]  : (r == 1) ? acc[1]  : (r == 2) ? acc[2]  : acc[3];
  const float gx  = (r == 0) ? acc[4]  : (r == 1) ? acc[5]  : (r == 2) ? acc[6]  : acc[7];
  const float gy  = (r == 0) ? acc[8]  : (r == 1) ? acc[9]  : (r == 2) ? acc[10] : acc[11];
  const float gz  = (r == 0) ? acc[12] : (r == 1) ? acc[13] : (r == 2) ? acc[14] : acc[15];

  const float n0 = __shfl(nacc0, a);
  const float n1 = __shfl(nacc1, a);
  const float n2 = __shfl(nacc2, a);
  const float n3 = __shfl(nacc3, a);
  const float nearS = (r == 0) ? n0 : (r == 1) ? n1 : (r == 2) ? n2 : n3;

  const float od = (a == 1) ?  H * gx : (a == 2) ?  H * gy : (a == 3) ?  H * gz :
                   (a == 4) ? -H * gx : (a == 5) ? -H * gy : (a == 6) ? -H * gz : 0.0f;
  const float mid = pot + od + nearS;

  // self terms, closed form (exact-erf constants)
  const float KAr  = (r == 0) ? KA[0]   : (r == 1) ? KA[1]   : (r == 2) ? KA[2]   : KA[3];
  const float PH1r = (r == 0) ? PH1C[0] : (r == 1) ? PH1C[1] : (r == 2) ? PH1C[2] : PH1C[3];
  const float DDr  = (r == 0) ? DDC[0]  : (r == 1) ? DDC[1]  : (r == 2) ? DDC[2]  : DDC[3];
  const float qax  = (a == 1 || a == 4) ? oc.y : (a == 2 || a == 5) ? oc.z : oc.w;
  const float sgn  = (a >= 4) ? -1.0f : 1.0f;
  const float selfSum = (a == 0) ? (oc.x * KAr)
                                 : __builtin_fmaf(oc.x, PH1r, sgn * qax * DDr);
  const float selfv = KCOUL * selfSum;
  const float featv = __builtin_fmaf(KCOUL, mid, selfv);

  // ---- projection via shfl; lanes 0..15 write features, 16..31 self ----
  const int k = (c < 16) ? c : (c < 32 ? c - 16 : 0);
  int idx1, idx2;
  if (k < 4) {
    idx1 = k; idx2 = 0;
  } else {
    const int q  = k - 4;
    const int rr = q / 3;
    const int comp = q - 3 * rr;
    const int j1 = (comp == 0) ? 2 : (comp == 1) ? 3 : 1;
    const int j2 = (comp == 0) ? 5 : (comp == 1) ? 6 : 4;
    idx1 = j1 * 4 + rr; idx2 = j2 * 4 + rr;
  }
  const float f1 = __shfl(featv, idx1), f2 = __shfl(featv, idx2);
  const float s1 = __shfl(selfv, idx1), s2 = __shfl(selfv, idx2);
  const float F  = (k < 4) ? f1 : HALF_L1 * (f1 - f2);
  const float S  = (k < 4) ? s1 : HALF_L1 * (s1 - s2);

  if (c < 16)      out[(size_t)b * 16 + c] = F;
  else if (c < 32) out[(size_t)MTOT * 16 + (size_t)b * 16 + (c - 16)] = S;
}

} // namespace

extern "C" void kernel_launch(void* const* d_in, const int* in_sizes, int n_in,
                              void* d_out, int out_size, void* d_ws, size_t ws_size,
                              hipStream_t stream) {
  const float* sf  = (const float*)d_in[0];   // source_feats (4096,1,4)
  const float* pos = (const float*)d_in[1];   // node_positions (4096,3)
  float* out = (float*)d_out;
  es_main<<<4096, 64, 0, stream>>>(sf, pos, out);
}